// Round 3
// baseline (125.894 us; speedup 1.0000x reference)
//
#include <hip/hip_runtime.h>
#include <cstdint>
#include <cstddef>

#define BB 8
#define NN 48
#define DD 33
#define XS 40            // xw/sw/ct row stride in floats (16B-aligned, zero-padded)
#define KP 128           // merged-K: [0,40)=xi*xj, [40,80)=xi*s, [80,120)=xj*s, 120=const
#define HH 32
#define MM (NN*NN)       // 2304 rows (i,j)
#define NC (NN*HH)       // 1536 cols (k,h)
#define TILE 96
#define TM (MM/TILE)     // 24
#define TN (NC/TILE)     // 16
#define LDK 136          // LDS row stride f16 (+8 pad -> only free 2-way aliasing)

typedef __attribute__((ext_vector_type(8))) _Float16 f16x8;
typedef __attribute__((ext_vector_type(4))) float f32x4;

// ---- Kernel A: gather xw (padded), s = mean_i x, transpose coefs -> ct, zero hsum --
__global__ void k_setup(const int* __restrict__ xcat, const float* __restrict__ xfeat,
                        const float* __restrict__ embed, const float* __restrict__ coefs,
                        float* __restrict__ xw, float* __restrict__ sw,
                        float* __restrict__ ct, float* __restrict__ hsum) {
    int b = blockIdx.x, t = threadIdx.x;
    if (b < BB) {
        for (int idx = t; idx < NN * XS; idx += 256) {
            int i = idx / XS, d = idx - i * XS;
            float v = 0.f;
            if (d < 32)       v = embed[xcat[b * NN + i] * 32 + d];
            else if (d == 32) v = xfeat[b * NN + i];
            xw[b * NN * XS + idx] = v;
        }
        if (t < HH) hsum[b * HH + t] = 0.f;
        __syncthreads();
        if (t < XS) {
            float a = 0.f;
            for (int i = 0; i < NN; ++i) a += xw[b * NN * XS + i * XS + t];
            sw[b * XS + t] = a * (1.0f / 48.0f);
        }
    } else {
        // ct[(q*32+h)*40 + d] = coefs[(d*8+q)*32 + h], zero-padded d>=33
        for (int idx = t; idx < 8 * HH * XS; idx += 256) {
            int qh = idx / XS, d = idx - qh * XS;
            int q = qh >> 5, h = qh & 31;
            ct[idx] = (d < DD) ? coefs[(d * 8 + q) * HH + h] : 0.f;
        }
    }
}

// ---- Kernel B: build D'[(b,k,h), 128] fp16 ----------------------------------------
__global__ void k_buildD(const float* __restrict__ xw, const float* __restrict__ sw,
                         const float* __restrict__ ct, const float* __restrict__ eq_bias,
                         _Float16* __restrict__ Dw) {
    int idx = blockIdx.x * 256 + threadIdx.x;       // [0, 196608)
    int rowid = idx >> 4, d0 = (idx & 15) * 8;
    int b = rowid / NC, n = rowid - b * NC;
    int k = n >> 5, h = n & 31;
    const float* xk = xw + (b * NN + k) * XS;
    const float* sb = sw + b * XS;
    f16x8 v;
    if (d0 < 120) {
        int seg = (d0 >= 80) ? 2 : (d0 >= 40) ? 1 : 0;
        int d = d0 - seg * 40;
        const int QA[3] = {0, 2, 1}, QB[3] = {3, 6, 5};
        const float* ca = ct + (QA[seg] * HH + h) * XS + d;
        const float* cb = ct + (QB[seg] * HH + h) * XS + d;
        f32x4 ca0 = *(const f32x4*)(ca),     ca1 = *(const f32x4*)(ca + 4);
        f32x4 cb0 = *(const f32x4*)(cb),     cb1 = *(const f32x4*)(cb + 4);
        f32x4 xk0 = *(const f32x4*)(xk + d), xk1 = *(const f32x4*)(xk + d + 4);
        f32x4 sb0 = *(const f32x4*)(sb + d), sb1 = *(const f32x4*)(sb + d + 4);
        f32x4 r0 = ca0 * xk0 + cb0 * sb0;
        f32x4 r1 = ca1 * xk1 + cb1 * sb1;
        for (int e = 0; e < 4; ++e) { v[e] = (_Float16)r0[e]; v[4 + e] = (_Float16)r1[e]; }
    } else {
        const float* c4 = ct + (4 * HH + h) * XS;
        const float* c7 = ct + (7 * HH + h) * XS;
        float g = 0.f;
        for (int d = 0; d < DD; ++d) {
            float sd = sb[d];
            g += sd * sd * (c4[d] * xk[d] + c7[d] * sd);
        }
        v = (f16x8){0, 0, 0, 0, 0, 0, 0, 0};
        v[0] = (_Float16)(g + eq_bias[h]);
    }
    *(f16x8*)&Dw[(size_t)rowid * KP + d0] = v;
}

// ---- Kernel C: 96x96 MFMA GEMM; A-tile built in-kernel from xw; relu + h-sum ------
__global__ __launch_bounds__(256) void k_gemm(const float* __restrict__ xw,
                                              const float* __restrict__ sw,
                                              const _Float16* __restrict__ Dw,
                                              float* __restrict__ hsum) {
    __shared__ __align__(16) _Float16 As[TILE][LDK];
    __shared__ __align__(16) _Float16 Bs[TILE][LDK];
    __shared__ float hacc[HH];
    int t = threadIdx.x;
    int bx = blockIdx.x, by = blockIdx.y, b = blockIdx.z;
    int M0 = by * TILE, N0 = bx * TILE;
    if (t < HH) hacc[t] = 0.f;

    const _Float16* Dg = Dw + ((size_t)(b * NC + N0)) * KP;
    const float* xb = xw + b * NN * XS;
    const float* sb = sw + b * XS;

    for (int c = 0; c < 6; ++c) {
        int ch = c * 256 + t;
        int row = ch >> 4, d0 = (ch & 15) * 8;
        // B-tile: straight copy from Dw
        *(f16x8*)&Bs[row][d0] = *(const f16x8*)(Dg + row * KP + d0);
        // A-tile: build from xw (L1-hot, 7.7 KB/batch)
        int grow = M0 + row;
        int i = grow / NN, j = grow - i * NN;
        f16x8 v;
        if (d0 < 120) {
            int seg = (d0 >= 80) ? 2 : (d0 >= 40) ? 1 : 0;
            int d = d0 - seg * 40;
            const float* p1 = (seg == 2) ? (xb + j * XS) : (xb + i * XS);
            const float* p2 = (seg == 0) ? (xb + j * XS) : sb;
            f32x4 a0 = *(const f32x4*)(p1 + d), a1 = *(const f32x4*)(p1 + d + 4);
            f32x4 b0 = *(const f32x4*)(p2 + d), b1 = *(const f32x4*)(p2 + d + 4);
            f32x4 r0 = a0 * b0, r1 = a1 * b1;
            for (int e = 0; e < 4; ++e) { v[e] = (_Float16)r0[e]; v[4 + e] = (_Float16)r1[e]; }
        } else {
            v = (f16x8){0, 0, 0, 0, 0, 0, 0, 0};
            v[0] = (_Float16)1.f;
        }
        *(f16x8*)&As[row][d0] = v;
    }
    __syncthreads();

    int lane = t & 63, wave = t >> 6;
    int wm = (wave >> 1) * 48, wn = (wave & 1) * 48;
    int lrow = lane & 15, quad = lane >> 4;

    f32x4 acc[3][3];
    for (int mt = 0; mt < 3; ++mt)
        for (int nt = 0; nt < 3; ++nt)
            acc[mt][nt] = (f32x4){0.f, 0.f, 0.f, 0.f};

    for (int ks = 0; ks < 4; ++ks) {
        f16x8 af[3], bf[3];
        for (int mt = 0; mt < 3; ++mt)
            af[mt] = *(const f16x8*)&As[wm + mt * 16 + lrow][ks * 32 + quad * 8];
        for (int nt = 0; nt < 3; ++nt)
            bf[nt] = *(const f16x8*)&Bs[wn + nt * 16 + lrow][ks * 32 + quad * 8];
        for (int mt = 0; mt < 3; ++mt)
            for (int nt = 0; nt < 3; ++nt)
                acc[mt][nt] = __builtin_amdgcn_mfma_f32_16x16x32_f16(af[mt], bf[nt], acc[mt][nt], 0, 0, 0);
    }

    float fs[3] = {0.f, 0.f, 0.f};
    for (int mt = 0; mt < 3; ++mt)
        for (int nt = 0; nt < 3; ++nt)
            for (int r = 0; r < 4; ++r)
                fs[nt] += fmaxf(acc[mt][nt][r], 0.f);
    for (int nt = 0; nt < 3; ++nt) {
        int h = (N0 + wn + nt * 16 + lrow) & 31;
        atomicAdd(&hacc[h], fs[nt]);
    }
    __syncthreads();
    if (t < HH) atomicAdd(&hsum[b * HH + t], hacc[t]);
}

// ---- Kernel D: out[b] = relu(hsum/48^3) @ out_w + out_b ---------------------------
__global__ void k_final(const float* __restrict__ hsum, const float* __restrict__ out_w,
                        const float* __restrict__ out_b, float* __restrict__ out) {
    __shared__ float red[BB * HH];
    int t = threadIdx.x;
    int h = t & 31;
    red[t] = fmaxf(hsum[t] * (1.0f / 110592.0f), 0.f) * out_w[h];
    __syncthreads();
    if (t < BB) {
        float a = 0.f;
        for (int x = 0; x < HH; ++x) a += red[t * HH + x];
        out[t] = a + out_b[0];
    }
}

extern "C" void kernel_launch(void* const* d_in, const int* in_sizes, int n_in,
                              void* d_out, int out_size, void* d_ws, size_t ws_size,
                              hipStream_t stream) {
    (void)in_sizes; (void)n_in; (void)out_size; (void)ws_size;
    const int*   xcat    = (const int*)d_in[0];
    const float* xfeat   = (const float*)d_in[1];
    const float* embed   = (const float*)d_in[2];
    const float* coefs   = (const float*)d_in[3];
    const float* eq_bias = (const float*)d_in[4];
    const float* out_w   = (const float*)d_in[5];
    const float* out_b   = (const float*)d_in[6];
    float* out = (float*)d_out;

    // Workspace layout (16B-aligned), total ~3.25 MB
    char* w = (char*)d_ws;
    float*    xw   = (float*)(w + 0);        // 8*48*40 f32 = 61440 B
    float*    sw   = (float*)(w + 61440);    // 8*40 f32    = 1280 B
    float*    ct   = (float*)(w + 62720);    // 8*32*40 f32 = 40960 B
    float*    hsum = (float*)(w + 103680);   // 8*32 f32    = 1024 B
    _Float16* Dw   = (_Float16*)(w + 104704);// 8*1536*128 f16 = 3145728 B

    k_setup<<<dim3(BB + 1), dim3(256), 0, stream>>>(xcat, xfeat, embed, coefs, xw, sw, ct, hsum);
    k_buildD<<<dim3(768), dim3(256), 0, stream>>>(xw, sw, ct, eq_bias, Dw);
    k_gemm<<<dim3(TN, TM, BB), dim3(256), 0, stream>>>(xw, sw, Dw, hsum);
    k_final<<<dim3(1), dim3(256), 0, stream>>>(hsum, out_w, out_b, out);
}

// Round 4
// 125.177 us; speedup vs baseline: 1.0057x; 1.0057x over previous
//
#include <hip/hip_runtime.h>
#include <cstdint>
#include <cstddef>

#define BB 8
#define NN 48
#define DD 33
#define XS 40            // xw/sw/ct row stride in floats (16B-aligned, zero-padded)
#define KP 128           // merged-K: [0,40)=xi*xj, [40,80)=xi*s, [80,120)=xj*s, 120=const
#define HH 32
#define MM (NN*NN)       // 2304 rows (i,j)
#define NC (NN*HH)       // 1536 cols (k,h)
#define TILE 96
#define TM (MM/TILE)     // 24
#define TN (NC/TILE)     // 16
#define NBLK (TM*TN)     // 384 blocks per batch
#define LDK 136          // LDS row stride f16 (+8 pad)

typedef __attribute__((ext_vector_type(8))) _Float16 f16x8;
typedef __attribute__((ext_vector_type(4))) float f32x4;

// ---- Kernel A: gather xw (padded), s = mean_i x, transpose coefs -> ct -------------
__global__ void k_setup(const int* __restrict__ xcat, const float* __restrict__ xfeat,
                        const float* __restrict__ embed, const float* __restrict__ coefs,
                        float* __restrict__ xw, float* __restrict__ sw,
                        float* __restrict__ ct) {
    int b = blockIdx.x, t = threadIdx.x;
    if (b < BB) {
        for (int idx = t; idx < NN * XS; idx += 256) {
            int i = idx / XS, d = idx - i * XS;
            float v = 0.f;
            if (d < 32)       v = embed[xcat[b * NN + i] * 32 + d];
            else if (d == 32) v = xfeat[b * NN + i];
            xw[b * NN * XS + idx] = v;
        }
        __syncthreads();
        if (t < XS) {
            float a = 0.f;
            for (int i = 0; i < NN; ++i) a += xw[b * NN * XS + i * XS + t];
            sw[b * XS + t] = a * (1.0f / 48.0f);
        }
    } else {
        // ct[(q*32+h)*40 + d] = coefs[(d*8+q)*32 + h], zero-padded d>=33
        for (int idx = t; idx < 8 * HH * XS; idx += 256) {
            int qh = idx / XS, d = idx - qh * XS;
            int q = qh >> 5, h = qh & 31;
            ct[idx] = (d < DD) ? coefs[(d * 8 + q) * HH + h] : 0.f;
        }
    }
}

// ---- Kernel B: build D'[(b,k,h), 128] fp16 ----------------------------------------
__global__ void k_buildD(const float* __restrict__ xw, const float* __restrict__ sw,
                         const float* __restrict__ ct, const float* __restrict__ eq_bias,
                         _Float16* __restrict__ Dw) {
    int idx = blockIdx.x * 256 + threadIdx.x;       // [0, 196608)
    int rowid = idx >> 4, d0 = (idx & 15) * 8;
    int b = rowid / NC, n = rowid - b * NC;
    int k = n >> 5, h = n & 31;
    const float* xk = xw + (b * NN + k) * XS;
    const float* sb = sw + b * XS;
    f16x8 v;
    if (d0 < 120) {
        int seg = (d0 >= 80) ? 2 : (d0 >= 40) ? 1 : 0;
        int d = d0 - seg * 40;
        const int QA[3] = {0, 2, 1}, QB[3] = {3, 6, 5};
        const float* ca = ct + (QA[seg] * HH + h) * XS + d;
        const float* cb = ct + (QB[seg] * HH + h) * XS + d;
        f32x4 ca0 = *(const f32x4*)(ca),     ca1 = *(const f32x4*)(ca + 4);
        f32x4 cb0 = *(const f32x4*)(cb),     cb1 = *(const f32x4*)(cb + 4);
        f32x4 xk0 = *(const f32x4*)(xk + d), xk1 = *(const f32x4*)(xk + d + 4);
        f32x4 sb0 = *(const f32x4*)(sb + d), sb1 = *(const f32x4*)(sb + d + 4);
        f32x4 r0 = ca0 * xk0 + cb0 * sb0;
        f32x4 r1 = ca1 * xk1 + cb1 * sb1;
        for (int e = 0; e < 4; ++e) { v[e] = (_Float16)r0[e]; v[4 + e] = (_Float16)r1[e]; }
    } else {
        const float* c4 = ct + (4 * HH + h) * XS;
        const float* c7 = ct + (7 * HH + h) * XS;
        float g = 0.f;
        for (int d = 0; d < DD; ++d) {
            float sd = sb[d];
            g += sd * sd * (c4[d] * xk[d] + c7[d] * sd);
        }
        v = (f16x8){0, 0, 0, 0, 0, 0, 0, 0};
        v[0] = (_Float16)(g + eq_bias[h]);
    }
    *(f16x8*)&Dw[(size_t)rowid * KP + d0] = v;
}

// ---- Kernel C: 96x96 MFMA GEMM; A-tile built in-kernel; relu + h-sum -> partials --
__global__ __launch_bounds__(256) void k_gemm(const float* __restrict__ xw,
                                              const float* __restrict__ sw,
                                              const _Float16* __restrict__ Dw,
                                              float* __restrict__ partials) {
    __shared__ __align__(16) _Float16 As[TILE][LDK];
    __shared__ __align__(16) _Float16 Bs[TILE][LDK];
    __shared__ float hacc[HH];
    int t = threadIdx.x;
    int bx = blockIdx.x, by = blockIdx.y, b = blockIdx.z;
    int M0 = by * TILE, N0 = bx * TILE;
    if (t < HH) hacc[t] = 0.f;

    const _Float16* Dg = Dw + ((size_t)(b * NC + N0)) * KP;
    const float* xb = xw + b * NN * XS;
    const float* sb = sw + b * XS;

    for (int c = 0; c < 6; ++c) {
        int ch = c * 256 + t;
        int row = ch >> 4, d0 = (ch & 15) * 8;
        *(f16x8*)&Bs[row][d0] = *(const f16x8*)(Dg + row * KP + d0);
        int grow = M0 + row;
        int i = grow / NN, j = grow - i * NN;
        f16x8 v;
        if (d0 < 120) {
            int seg = (d0 >= 80) ? 2 : (d0 >= 40) ? 1 : 0;
            int d = d0 - seg * 40;
            const float* p1 = (seg == 2) ? (xb + j * XS) : (xb + i * XS);
            const float* p2 = (seg == 0) ? (xb + j * XS) : sb;
            f32x4 a0 = *(const f32x4*)(p1 + d), a1 = *(const f32x4*)(p1 + d + 4);
            f32x4 b0 = *(const f32x4*)(p2 + d), b1 = *(const f32x4*)(p2 + d + 4);
            f32x4 r0 = a0 * b0, r1 = a1 * b1;
            for (int e = 0; e < 4; ++e) { v[e] = (_Float16)r0[e]; v[4 + e] = (_Float16)r1[e]; }
        } else {
            v = (f16x8){0, 0, 0, 0, 0, 0, 0, 0};
            v[0] = (_Float16)1.f;
        }
        *(f16x8*)&As[row][d0] = v;
    }
    __syncthreads();

    int lane = t & 63, wave = t >> 6;
    int wm = (wave >> 1) * 48, wn = (wave & 1) * 48;
    int lrow = lane & 15, quad = lane >> 4;

    f32x4 acc[3][3];
    for (int mt = 0; mt < 3; ++mt)
        for (int nt = 0; nt < 3; ++nt)
            acc[mt][nt] = (f32x4){0.f, 0.f, 0.f, 0.f};

    for (int ks = 0; ks < 4; ++ks) {
        f16x8 af[3], bf[3];
        for (int mt = 0; mt < 3; ++mt)
            af[mt] = *(const f16x8*)&As[wm + mt * 16 + lrow][ks * 32 + quad * 8];
        for (int nt = 0; nt < 3; ++nt)
            bf[nt] = *(const f16x8*)&Bs[wn + nt * 16 + lrow][ks * 32 + quad * 8];
        for (int mt = 0; mt < 3; ++mt)
            for (int nt = 0; nt < 3; ++nt)
                acc[mt][nt] = __builtin_amdgcn_mfma_f32_16x16x32_f16(af[mt], bf[nt], acc[mt][nt], 0, 0, 0);
    }

    float fs[3] = {0.f, 0.f, 0.f};
    for (int mt = 0; mt < 3; ++mt)
        for (int nt = 0; nt < 3; ++nt)
            for (int r = 0; r < 4; ++r)
                fs[nt] += fmaxf(acc[mt][nt][r], 0.f);
    for (int nt = 0; nt < 3; ++nt) {
        int h = (N0 + wn + nt * 16 + lrow) & 31;
        atomicAdd(&hacc[h], fs[nt]);
    }
    __syncthreads();
    if (t < HH) {
        int blockLin = by * TN + bx;
        partials[((size_t)b * NBLK + blockLin) * HH + t] = hacc[t];
    }
}

// ---- Kernel D: per-batch reduce -> relu(mean) @ out_w + out_b ---------------------
__global__ void k_final(const float* __restrict__ partials, const float* __restrict__ out_w,
                        const float* __restrict__ out_b, float* __restrict__ out) {
    __shared__ float red[256];
    int b = blockIdx.x, t = threadIdx.x;
    int h = t & 31, g = t >> 5;
    float a = 0.f;
    for (int p = g; p < NBLK; p += 8) a += partials[((size_t)b * NBLK + p) * HH + h];
    red[t] = a;
    __syncthreads();
    if (t < HH) {
        float tot = 0.f;
        for (int gg = 0; gg < 8; ++gg) tot += red[gg * 32 + t];
        float m = tot * (1.0f / 110592.0f);
        red[t] = fmaxf(m, 0.f) * out_w[t];
    }
    __syncthreads();
    if (t == 0) {
        float o = 0.f;
        for (int h2 = 0; h2 < HH; ++h2) o += red[h2];
        out[b] = o + out_b[0];
    }
}

extern "C" void kernel_launch(void* const* d_in, const int* in_sizes, int n_in,
                              void* d_out, int out_size, void* d_ws, size_t ws_size,
                              hipStream_t stream) {
    (void)in_sizes; (void)n_in; (void)out_size; (void)ws_size;
    const int*   xcat    = (const int*)d_in[0];
    const float* xfeat   = (const float*)d_in[1];
    const float* embed   = (const float*)d_in[2];
    const float* coefs   = (const float*)d_in[3];
    const float* eq_bias = (const float*)d_in[4];
    const float* out_w   = (const float*)d_in[5];
    const float* out_b   = (const float*)d_in[6];
    float* out = (float*)d_out;

    // Workspace layout (16B-aligned), total ~3.7 MB
    char* w = (char*)d_ws;
    float*    xw       = (float*)(w + 0);        // 8*48*40 f32 = 61440 B
    float*    sw       = (float*)(w + 61440);    // 8*40 f32    = 1280 B
    float*    ct       = (float*)(w + 62720);    // 8*32*40 f32 = 40960 B
    _Float16* Dw       = (_Float16*)(w + 103680);// 8*1536*128 f16 = 3145728 B
    float*    partials = (float*)(w + 3249408);  // 3072*32 f32 = 393216 B

    k_setup<<<dim3(BB + 1), dim3(256), 0, stream>>>(xcat, xfeat, embed, coefs, xw, sw, ct);
    k_buildD<<<dim3(768), dim3(256), 0, stream>>>(xw, sw, ct, eq_bias, Dw);
    k_gemm<<<dim3(TN, TM, BB), dim3(256), 0, stream>>>(xw, sw, Dw, partials);
    k_final<<<dim3(BB), dim3(256), 0, stream>>>(partials, out_w, out_b, out);
}